// Round 4
// baseline (260.506 us; speedup 1.0000x reference)
//
#include <hip/hip_runtime.h>

// CRF NLL: B=256, S=2048, T=64.
// Sequence-parallel forward algorithm, KC=64 chunks/batch, WARM=48 warmup steps
// (Birkhoff contraction fixes direction; V_c = chunk log-scale growth;
// logZ = sum_c V_c + final lse). Denominator all-to-all done in the matrix
// engine: per step Y(64x16) = E^T(64x64) x Q(64x16) via 8x mfma_f32_16x16x32_f16
// with E^T persistent in VGPRs; feedback is pure cvt_pkrtz (D's per-lane tag set
// == B's required tag set), zero LDS in the recurrence except one ds_bpermute
// for the per-stream renorm reference.
//
// Round-3 post-mortem: 768 waves on 1024 SIMDs -> wall = steps x serial chain
// (~2000 cyc/step measured; VALUBusy 10%). This revision attacks latency:
//   - KC 32->64: steps/stream 112->80 (LC=32, warmup unchanged).
//   - ILP-2: each wave carries TWO independent 16-stream groups (32 chunks of
//     one batch); the two chains interleave in each other's stall bubbles
//     (16 MFMAs + 2 pipelined bpermutes per round).
//   - Reference tile (tf0) MFMAs first + early shfl: bpermute latency hides
//     under the remaining 12 MFMAs.
// Numerator: 256 dedicated gather-waves, unchanged.
#define BB 256
#define SS 2048
#define TT 64
#define KC 64
#define LC 32               // main steps per chunk
#define WARM 48
#define NSTEP (WARM + LC)   // 80 steps per stream (last OOB-predicated)
#define DEN_WAVES (BB * 2)  // 512 denominator waves (2 groups x 16 streams)
#define NSLOT 128
#define SLOT_STRIDE 32      // floats; slots 128 B apart
#define LN2 0.69314718055994531f
#define LOG2E 1.4426950408889634f

typedef __fp16 half2v __attribute__((ext_vector_type(2)));
typedef __fp16 half8v __attribute__((ext_vector_type(8)));
typedef float float4v __attribute__((ext_vector_type(4)));

__device__ __forceinline__ float4v mfma16(half8v a, half8v b, float4v c) {
  return __builtin_amdgcn_mfma_f32_16x16x32_f16(a, b, c, 0, 0, 0);
}

struct GS {                 // per-group recurrence state (all registers)
  half8v B0, B1;            // q as B-fragments, tag = 32kt+16(e>>2)+4g+(e&3)
  float4v tf0, tf1, tf2, tf3;  // last step's scaled f32 q (tags 16mt+4g+r)
  float4v bufA[4], bufB[4]; // emission double-buffer
  float q0cur;              // normalized tag-0 value (uniform per stream)
  int esum, nsteps;         // exact exponent bookkeeping
  float sS, gamma;
  int c, base;
};

__device__ __forceinline__ void pf(float4v (&buf)[4], const float* emB,
                                   int base, int idx, int g) {
  int p = base + idx;
  p = p < 0 ? 0 : (p > SS - 1 ? SS - 1 : p);  // clamp: garbage discarded at
  const float* r = emB + (size_t)p * TT + 4 * g;  // boundaries
#pragma unroll
  for (int mt = 0; mt < 4; ++mt) buf[mt] = *(const float4v*)(r + 16 * mt);
}

__device__ __forceinline__ void exp4all(float4v (&x)[4], const float4v (&buf)[4]) {
#pragma unroll
  for (int mt = 0; mt < 4; ++mt)
#pragma unroll
    for (int e = 0; e < 4; ++e) x[mt][e] = __expf(buf[mt][e]);
}

__device__ __forceinline__ void repack(GS& a, float sc) {
  a.tf0 *= sc; a.tf1 *= sc; a.tf2 *= sc; a.tf3 *= sc;
  half2v p;
  p = __builtin_amdgcn_cvt_pkrtz(a.tf0[0], a.tf0[1]); a.B0[0] = p[0]; a.B0[1] = p[1];
  p = __builtin_amdgcn_cvt_pkrtz(a.tf0[2], a.tf0[3]); a.B0[2] = p[0]; a.B0[3] = p[1];
  p = __builtin_amdgcn_cvt_pkrtz(a.tf1[0], a.tf1[1]); a.B0[4] = p[0]; a.B0[5] = p[1];
  p = __builtin_amdgcn_cvt_pkrtz(a.tf1[2], a.tf1[3]); a.B0[6] = p[0]; a.B0[7] = p[1];
  p = __builtin_amdgcn_cvt_pkrtz(a.tf2[0], a.tf2[1]); a.B1[0] = p[0]; a.B1[1] = p[1];
  p = __builtin_amdgcn_cvt_pkrtz(a.tf2[2], a.tf2[3]); a.B1[2] = p[0]; a.B1[3] = p[1];
  p = __builtin_amdgcn_cvt_pkrtz(a.tf3[0], a.tf3[1]); a.B1[4] = p[0]; a.B1[5] = p[1];
  p = __builtin_amdgcn_cvt_pkrtz(a.tf3[2], a.tf3[3]); a.B1[6] = p[0]; a.B1[7] = p[1];
}

// one recurrence step for BOTH groups, hand-interleaved:
// tf0 MFMAs first, shfl issued early so its LDS latency hides under the
// remaining 12 MFMAs; the two chains fill each other's bubbles.
__device__ __forceinline__ void core2(const half8v (&A)[4][2], GS& a, GS& b,
                                      const float4v (&xa)[4],
                                      const float4v (&xb)[4], int s) {
  const float4v z = {0.f, 0.f, 0.f, 0.f};
  a.tf0 = mfma16(A[0][0], a.B0, z);
  a.tf0 = mfma16(A[0][1], a.B1, a.tf0);
  b.tf0 = mfma16(A[0][0], b.B0, z);
  b.tf0 = mfma16(A[0][1], b.B1, b.tf0);
  float rva = a.tf0[0] * xa[0][0];  // tag-4g pre-norm value; lane (0,s) = tag 0
  float rvb = b.tf0[0] * xb[0][0];
  float va = __shfl(rva, s, 64);    // stream-s tag-0 reference (g=0 lane)
  float vb = __shfl(rvb, s, 64);
  a.tf1 = mfma16(A[1][0], a.B0, z);
  a.tf1 = mfma16(A[1][1], a.B1, a.tf1);
  b.tf1 = mfma16(A[1][0], b.B0, z);
  b.tf1 = mfma16(A[1][1], b.B1, b.tf1);
  a.tf2 = mfma16(A[2][0], a.B0, z);
  a.tf2 = mfma16(A[2][1], a.B1, a.tf2);
  b.tf2 = mfma16(A[2][0], b.B0, z);
  b.tf2 = mfma16(A[2][1], b.B1, b.tf2);
  a.tf3 = mfma16(A[3][0], a.B0, z);
  a.tf3 = mfma16(A[3][1], a.B1, a.tf3);
  b.tf3 = mfma16(A[3][0], b.B0, z);
  b.tf3 = mfma16(A[3][1], b.B1, b.tf3);
  a.tf0 *= xa[0]; a.tf1 *= xa[1]; a.tf2 *= xa[2]; a.tf3 *= xa[3];
  b.tf0 *= xb[0]; b.tf1 *= xb[1]; b.tf2 *= xb[2]; b.tf3 *= xb[3];
  int eba = __builtin_bit_cast(int, va) & 0x7f800000;
  int ebb = __builtin_bit_cast(int, vb) & 0x7f800000;
  float sca = __builtin_bit_cast(float, 0x7C000000 - eba);  // 2^(121-e), exact
  float scb = __builtin_bit_cast(float, 0x7C000000 - ebb);
  a.esum += eba >> 23; a.nsteps += 1; a.q0cur = va * sca;
  b.esum += ebb >> 23; b.nsteps += 1; b.q0cur = vb * scb;
  repack(a, sca);
  repack(b, scb);
}

__global__ __launch_bounds__(64) void crf_kernel(
    const float* __restrict__ em, const float* __restrict__ startT,
    const float* __restrict__ endT, const float* __restrict__ trans,
    const int* __restrict__ tags, const int* __restrict__ mask,
    float* __restrict__ acc, int slotmask) {
  const int lane = threadIdx.x;

  if (blockIdx.x >= DEN_WAVES) {
    // ---------------- numerator: one wave per batch, pure gathers ----------
    const int bb = blockIdx.x - DEN_WAVES;
    const int* tg = tags + bb * SS;
    const int* mp = mask + bb * SS;
    const float* emb = em + (size_t)bb * SS * TT;
    float part = 0.f;
    int cnt = 0;
#pragma unroll 4
    for (int k = 0; k < SS / 64; ++k) {
      int i = k * 64 + lane;
      int m = mp[i];
      cnt += m;
      if (i >= 1 && m) {
        int t1 = tg[i], t0 = tg[i - 1];
        part += trans[t0 * TT + t1] + emb[(size_t)i * TT + t1];
      }
    }
#pragma unroll
    for (int o = 32; o > 0; o >>= 1) {
      part += __shfl_xor(part, o, 64);
      cnt += __shfl_xor(cnt, o, 64);
    }
    if (lane == 0) {
      int t0 = tg[0];
      float num = part + startT[t0] + emb[t0] + endT[tg[cnt - 1]];
      atomicAdd(acc + (size_t)(blockIdx.x & slotmask) * SLOT_STRIDE,
                -num * (1.0f / BB));
    }
    return;
  }

  // ---------------- denominator: 2 groups x 16 streams per wave ------------
  const int bb = blockIdx.x >> 1;
  const int h = blockIdx.x & 1;
  const int s = lane & 15;   // stream column
  const int g = lane >> 4;   // k-group / row-group
  const float* emB = em + (size_t)bb * SS * TT;
  const size_t rowb = (size_t)bb * SS;

  // A fragments: E^T, A[mt][kt][e] = exp(trans[k][m])*2^-5,
  // k = 32kt + 16(e>>2) + 4g + (e&3), m = 16mt + s. Shared by both groups.
  half8v A[4][2];
#pragma unroll
  for (int mt = 0; mt < 4; ++mt)
#pragma unroll
    for (int kt = 0; kt < 2; ++kt) {
      half8v f;
#pragma unroll
      for (int e = 0; e < 8; e += 2) {
        int k0 = 32 * kt + 16 * (e >> 2) + 4 * g + (e & 3);
        int m = 16 * mt + s;
        float v0 = __expf(trans[k0 * TT + m]) * 0.03125f;
        float v1 = __expf(trans[(k0 + 1) * TT + m]) * 0.03125f;
        half2v p = __builtin_amdgcn_cvt_pkrtz(v0, v1);
        f[e] = p[0];
        f[e + 1] = p[1];
      }
      A[mt][kt] = f;
    }

  GS ga, gb;
  ga.c = h * 32 + s;        // chunks 0..15 / 32..47
  gb.c = h * 32 + 16 + s;   // chunks 16..31 / 48..63
  ga.base = ga.c * LC - WARM + 1;
  gb.base = gb.c * LC - WARM + 1;
#pragma unroll
  for (int e = 0; e < 8; ++e) {
    ga.B0[e] = (__fp16)0.015625f;  // uniform 2^-6; warmup fixes direction
    ga.B1[e] = (__fp16)0.015625f;
    gb.B0[e] = (__fp16)0.015625f;
    gb.B1[e] = (__fp16)0.015625f;
  }
  ga.q0cur = 0.015625f; ga.esum = 0; ga.nsteps = 0; ga.sS = 0.f; ga.gamma = 0.f;
  gb.q0cur = 0.015625f; gb.esum = 0; gb.nsteps = 0; gb.sS = 0.f; gb.gamma = 0.f;

  pf(ga.bufA, emB, ga.base, 0, g);
  pf(gb.bufA, emB, gb.base, 0, g);
  pf(ga.bufB, emB, ga.base, 1, g);
  pf(gb.bufB, emB, gb.base, 1, g);

  for (int idx = 0; idx < NSTEP - 2; idx += 2) {  // steps 0..77 in pairs
    if (idx == WARM) {  // main-region start: capture scale / exact c=0 init
      ga.sS = __log2f(ga.q0cur) + (float)(6 + ga.esum - 116 * ga.nsteps);
      gb.sS = __log2f(gb.q0cur) + (float)(6 + gb.esum - 116 * gb.nsteps);
      if (ga.c == 0) {  // only group A (h=0,s=0 lanes); no cross-lane inside
        float aref = startT[0] + emB[0];
        ga.gamma = aref * LOG2E;
        ga.sS = 0.f;
        ga.esum = 0;
        ga.nsteps = 0;
        ga.q0cur = 0.015625f;
#pragma unroll
        for (int e = 0; e < 8; ++e) {
          int t0i = 16 * (e >> 2) + 4 * g + (e & 3);
          ga.B0[e] = (__fp16)(__expf(startT[t0i] + emB[t0i] - aref) * 0.015625f);
          ga.B1[e] = (__fp16)(__expf(startT[t0i + 32] + emB[t0i + 32] - aref) *
                              0.015625f);
        }
      }
    }
    {  // step idx
      float4v xa[4], xb[4];
      exp4all(xa, ga.bufA);
      exp4all(xb, gb.bufA);
      pf(ga.bufA, emB, ga.base, idx + 2, g);
      pf(gb.bufA, emB, gb.base, idx + 2, g);
      core2(A, ga, gb, xa, xb, s);
    }
    {  // step idx+1
      float4v xa[4], xb[4];
      exp4all(xa, ga.bufB);
      exp4all(xb, gb.bufB);
      pf(ga.bufB, emB, ga.base, idx + 3, g);
      pf(gb.bufB, emB, gb.base, idx + 3, g);
      core2(A, ga, gb, xa, xb, s);
    }
  }
  {  // step 78 (always in range: p = c*32+31 <= 2047)
    float4v xa[4], xb[4];
    exp4all(xa, ga.bufA);
    exp4all(xb, gb.bufA);
    core2(A, ga, gb, xa, xb, s);
  }
  {  // step 79: OOB for chunk 63 (p=2048) — convergent compute, predicated commit
    half8v oB0a = ga.B0, oB1a = ga.B1, oB0b = gb.B0, oB1b = gb.B1;
    float4v o0a = ga.tf0, o1a = ga.tf1, o2a = ga.tf2, o3a = ga.tf3;
    float4v o0b = gb.tf0, o1b = gb.tf1, o2b = gb.tf2, o3b = gb.tf3;
    int oea = ga.esum, ona = ga.nsteps, oeb = gb.esum, onb = gb.nsteps;
    float oqa = ga.q0cur, oqb = gb.q0cur;
    float4v xa[4], xb[4];
    exp4all(xa, ga.bufB);
    exp4all(xb, gb.bufB);
    core2(A, ga, gb, xa, xb, s);
    int pa = ga.base + (NSTEP - 1);
    int pca = pa > SS - 1 ? SS - 1 : pa;
    bool acta = (pa >= 1) && (pa <= SS - 1) && (mask[rowb + pca] != 0);
    if (!acta) {
      ga.B0 = oB0a; ga.B1 = oB1a; ga.esum = oea; ga.nsteps = ona; ga.q0cur = oqa;
      ga.tf0 = o0a; ga.tf1 = o1a; ga.tf2 = o2a; ga.tf3 = o3a;
    }
    int pb = gb.base + (NSTEP - 1);
    int pcb = pb > SS - 1 ? SS - 1 : pb;
    bool actb = (pb >= 1) && (pb <= SS - 1) && (mask[rowb + pcb] != 0);
    if (!actb) {
      gb.B0 = oB0b; gb.B1 = oB1b; gb.esum = oeb; gb.nsteps = onb; gb.q0cur = oqb;
      gb.tf0 = o0b; gb.tf1 = o1b; gb.tf2 = o2b; gb.tf3 = o3b;
    }
  }

  // chunk contributions: V_c = ln2 * (eS - sS), both groups
  float eSa = __log2f(ga.q0cur) + (float)(6 + ga.esum - 116 * ga.nsteps) + ga.gamma;
  float eSb = __log2f(gb.q0cur) + (float)(6 + gb.esum - 116 * gb.nsteps) + gb.gamma;
  float contrib = LN2 * ((eSa - ga.sS) + (eSb - gb.sS));

  // final logsumexp: only group B can hold c==KC-1 (computed convergently)
  {
    float q0l = __log2f(gb.q0cur);
    float4v ar0, ar1, ar2, ar3;
    float mx = -1e30f;
#pragma unroll
    for (int r = 0; r < 4; ++r) {
      ar0[r] = LN2 * (__log2f(gb.tf0[r]) - q0l) + endT[4 * g + r];
      ar1[r] = LN2 * (__log2f(gb.tf1[r]) - q0l) + endT[16 + 4 * g + r];
      ar2[r] = LN2 * (__log2f(gb.tf2[r]) - q0l) + endT[32 + 4 * g + r];
      ar3[r] = LN2 * (__log2f(gb.tf3[r]) - q0l) + endT[48 + 4 * g + r];
      mx = fmaxf(mx, fmaxf(fmaxf(ar0[r], ar1[r]), fmaxf(ar2[r], ar3[r])));
    }
    mx = fmaxf(mx, __shfl_xor(mx, 16, 64));
    mx = fmaxf(mx, __shfl_xor(mx, 32, 64));
    float ex = 0.f;
#pragma unroll
    for (int r = 0; r < 4; ++r)
      ex += __expf(ar0[r] - mx) + __expf(ar1[r] - mx) + __expf(ar2[r] - mx) +
            __expf(ar3[r] - mx);
    ex += __shfl_xor(ex, 16, 64);
    ex += __shfl_xor(ex, 32, 64);
    if (gb.c == KC - 1) contrib += mx + __logf(ex);
  }

  // one atomic per wave: sum contribs of the 32 streams (g==0 lanes only)
  float val = (g == 0) ? contrib : 0.f;
#pragma unroll
  for (int o = 32; o > 0; o >>= 1) val += __shfl_xor(val, o, 64);
  if (lane == 0)
    atomicAdd(acc + (size_t)(blockIdx.x & slotmask) * SLOT_STRIDE,
              val * (1.0f / BB));
}

__global__ __launch_bounds__(64) void reduce_kernel(const float* __restrict__ ws,
                                                    float* __restrict__ out) {
  float v = ws[(size_t)threadIdx.x * SLOT_STRIDE] +
            ws[(size_t)(threadIdx.x + 64) * SLOT_STRIDE];
#pragma unroll
  for (int o = 32; o > 0; o >>= 1) v += __shfl_xor(v, o, 64);
  if (threadIdx.x == 0) *out = v;
}

extern "C" void kernel_launch(void* const* d_in, const int* in_sizes, int n_in,
                              void* d_out, int out_size, void* d_ws, size_t ws_size,
                              hipStream_t stream) {
  const float* em = (const float*)d_in[0];
  const float* startT = (const float*)d_in[1];
  const float* endT = (const float*)d_in[2];
  const float* trans = (const float*)d_in[3];
  const int* tags = (const int*)d_in[4];
  const int* mask = (const int*)d_in[5];
  float* out = (float*)d_out;

  const size_t need = (size_t)NSLOT * SLOT_STRIDE * sizeof(float);
  if (d_ws && ws_size >= need) {
    (void)hipMemsetAsync(d_ws, 0, need, stream);
    crf_kernel<<<DEN_WAVES + BB, 64, 0, stream>>>(em, startT, endT, trans, tags,
                                                  mask, (float*)d_ws, NSLOT - 1);
    reduce_kernel<<<1, 64, 0, stream>>>((const float*)d_ws, out);
  } else {  // tiny-workspace fallback: single accumulator
    (void)hipMemsetAsync(out, 0, sizeof(float), stream);
    crf_kernel<<<DEN_WAVES + BB, 64, 0, stream>>>(em, startT, endT, trans, tags,
                                                  mask, out, 0);
  }
}

// Round 5
// 252.794 us; speedup vs baseline: 1.0305x; 1.0305x over previous
//
#include <hip/hip_runtime.h>

// CRF NLL: B=256, S=2048, T=64.
// Sequence-parallel forward algorithm, KC=64 chunks/batch, WARM=48 warmup steps
// (Birkhoff contraction fixes direction; V_c = chunk log-scale growth;
// logZ = sum_c V_c + final lse). Denominator all-to-all in the matrix engine:
// per step Y(64x16) = E^T(64x64) x Q(64x16) via 8x mfma_f32_16x16x32_f16, E^T
// persistent in VGPRs; feedback is pure cvt_pkrtz (D's per-lane tag set == B's
// required tag set); one ds_bpermute per step for the per-stream renorm ref.
//
// Round-4 post-mortem: step time ~1700-2000 cyc vs ~300-cyc register chain ->
// memory-latency stall (distance-2 prefetch, ~1 wave/SIMD, no TLP). This rev:
//   - 16 streams/wave, single group: 1024 den waves = 1/SIMD exactly (r3/r4
//     left 25-50% of SIMDs idle).
//   - Prefetch depth 4 (ring of 4 step-buffers in registers): ~4-step lookahead
//     covers HBM-miss latency (~900 cyc).
//   - XCD-grouped swizzle: the 4 waves of a batch (+ chunk neighbors) land on
//     one XCD so the 2.5x warmup re-reads of its 512 KB emission slab hit the
//     XCD's 4 MB L2 instead of L3/HBM.
// Numerator: 256 dedicated gather-waves, unchanged.
#define BB 256
#define SS 2048
#define TT 64
#define KC 64
#define LC 32               // main steps per chunk
#define WARM 48
#define NSTEP (WARM + LC)   // 80 steps per stream (last OOB-predicated)
#define DEN_WAVES (BB * 4)  // 1024 denominator waves (16 streams each)
#define NSLOT 128
#define SLOT_STRIDE 32      // floats; slots 128 B apart
#define LN2 0.69314718055994531f
#define LOG2E 1.4426950408889634f

typedef __fp16 half2v __attribute__((ext_vector_type(2)));
typedef __fp16 half8v __attribute__((ext_vector_type(8)));
typedef float float4v __attribute__((ext_vector_type(4)));

__device__ __forceinline__ float4v mfma16(half8v a, half8v b, float4v c) {
  return __builtin_amdgcn_mfma_f32_16x16x32_f16(a, b, c, 0, 0, 0);
}

__global__ __launch_bounds__(64) void crf_kernel(
    const float* __restrict__ em, const float* __restrict__ startT,
    const float* __restrict__ endT, const float* __restrict__ trans,
    const int* __restrict__ tags, const int* __restrict__ mask,
    float* __restrict__ acc, int slotmask) {
  const int lane = threadIdx.x;

  if (blockIdx.x >= DEN_WAVES) {
    // ---------------- numerator: one wave per batch, pure gathers ----------
    const int bb = blockIdx.x - DEN_WAVES;
    const int* tg = tags + bb * SS;
    const int* mp = mask + bb * SS;
    const float* emb = em + (size_t)bb * SS * TT;
    float part = 0.f;
    int cnt = 0;
#pragma unroll 4
    for (int k = 0; k < SS / 64; ++k) {
      int i = k * 64 + lane;
      int m = mp[i];
      cnt += m;
      if (i >= 1 && m) {
        int t1 = tg[i], t0 = tg[i - 1];
        part += trans[t0 * TT + t1] + emb[(size_t)i * TT + t1];
      }
    }
#pragma unroll
    for (int o = 32; o > 0; o >>= 1) {
      part += __shfl_xor(part, o, 64);
      cnt += __shfl_xor(cnt, o, 64);
    }
    if (lane == 0) {
      int t0 = tg[0];
      float num = part + startT[t0] + emb[t0] + endT[tg[cnt - 1]];
      atomicAdd(acc + (size_t)(blockIdx.x & slotmask) * SLOT_STRIDE,
                -num * (1.0f / BB));
    }
    return;
  }

  // ---------------- denominator: 16 streams per wave via MFMA --------------
  // XCD-grouped swizzle: physical wg w -> XCD w%8 (round-robin dispatch).
  // Give XCD x the contiguous logical range [x*128, x*128+128) so each XCD
  // owns 32 whole batches (L2-resident warmup overlap).
  const int w = blockIdx.x;
  const int L = (w & 7) * (DEN_WAVES / 8) + (w >> 3);
  const int bb = L >> 2;       // batch
  const int quarter = L & 3;   // which 16 chunks of the 64
  const int s = lane & 15;     // stream column
  const int g = lane >> 4;     // k-group / row-group
  const int c = quarter * 16 + s;  // this lane's stream = chunk index
  const float* emB = em + (size_t)bb * SS * TT;
  const size_t rowb = (size_t)bb * SS;

  // A fragments: E^T, A[mt][kt][e] = exp(trans[k][m])*2^-5,
  // k = 32kt + 16(e>>2) + 4g + (e&3), m = 16mt + s.
  half8v A[4][2];
#pragma unroll
  for (int mt = 0; mt < 4; ++mt)
#pragma unroll
    for (int kt = 0; kt < 2; ++kt) {
      half8v f;
#pragma unroll
      for (int e = 0; e < 8; e += 2) {
        int k0 = 32 * kt + 16 * (e >> 2) + 4 * g + (e & 3);
        int m = 16 * mt + s;
        float v0 = __expf(trans[k0 * TT + m]) * 0.03125f;
        float v1 = __expf(trans[(k0 + 1) * TT + m]) * 0.03125f;
        half2v p = __builtin_amdgcn_cvt_pkrtz(v0, v1);
        f[e] = p[0];
        f[e + 1] = p[1];
      }
      A[mt][kt] = f;
    }

  // state: q as B-fragments (f16), tag = 32kt + 16(e>>2) + 4g + (e&3)
  half8v B0, B1;
#pragma unroll
  for (int e = 0; e < 8; ++e) {
    B0[e] = (__fp16)0.015625f;  // uniform 2^-6; warmup fixes direction
    B1[e] = (__fp16)0.015625f;
  }
  float q0cur = 0.015625f;
  int esum = 0, nsteps = 0;
  float sS = 0.f, gamma = 0.f;
  float4v tf0, tf1, tf2, tf3;

  const int base = c * LC - WARM + 1;

  // ring of 4 step-buffers: slot k holds emissions for step idx with idx%4==k
  float4v buf[4][4];

  auto PF = [&](int slot, int idx) {
    int p = base + idx;
    p = p < 0 ? 0 : (p > SS - 1 ? SS - 1 : p);  // clamp; boundary garbage is
    const float* r = emB + (size_t)p * TT + 4 * g;  // discarded/predicated
#pragma unroll
    for (int mt = 0; mt < 4; ++mt) buf[slot][mt] = *(const float4v*)(r + 16 * mt);
  };
  auto CORE = [&](const float4v (&x)[4]) {
    const float4v z = {0.f, 0.f, 0.f, 0.f};
    tf0 = mfma16(A[0][0], B0, z);
    tf0 = mfma16(A[0][1], B1, tf0);
    float rv = tf0[0] * x[0][0];   // tag-4g pre-norm value; lane (0,s) = tag 0
    float v = __shfl(rv, s, 64);   // stream-s tag-0 reference (early: hides
    tf1 = mfma16(A[1][0], B0, z);  // bpermute latency under remaining MFMAs)
    tf1 = mfma16(A[1][1], B1, tf1);
    tf2 = mfma16(A[2][0], B0, z);
    tf2 = mfma16(A[2][1], B1, tf2);
    tf3 = mfma16(A[3][0], B0, z);
    tf3 = mfma16(A[3][1], B1, tf3);
    tf0 *= x[0]; tf1 *= x[1]; tf2 *= x[2]; tf3 *= x[3];
    int eb = __builtin_bit_cast(int, v) & 0x7f800000;
    float sc = __builtin_bit_cast(float, 0x7C000000 - eb);  // 2^(121-e), exact
    esum += eb >> 23;
    nsteps += 1;
    q0cur = v * sc;
    tf0 *= sc; tf1 *= sc; tf2 *= sc; tf3 *= sc;
    half2v p;
    p = __builtin_amdgcn_cvt_pkrtz(tf0[0], tf0[1]); B0[0] = p[0]; B0[1] = p[1];
    p = __builtin_amdgcn_cvt_pkrtz(tf0[2], tf0[3]); B0[2] = p[0]; B0[3] = p[1];
    p = __builtin_amdgcn_cvt_pkrtz(tf1[0], tf1[1]); B0[4] = p[0]; B0[5] = p[1];
    p = __builtin_amdgcn_cvt_pkrtz(tf1[2], tf1[3]); B0[6] = p[0]; B0[7] = p[1];
    p = __builtin_amdgcn_cvt_pkrtz(tf2[0], tf2[1]); B1[0] = p[0]; B1[1] = p[1];
    p = __builtin_amdgcn_cvt_pkrtz(tf2[2], tf2[3]); B1[2] = p[0]; B1[3] = p[1];
    p = __builtin_amdgcn_cvt_pkrtz(tf3[0], tf3[1]); B1[4] = p[0]; B1[5] = p[1];
    p = __builtin_amdgcn_cvt_pkrtz(tf3[2], tf3[3]); B1[6] = p[0]; B1[7] = p[1];
  };
  auto STEP = [&](int slot, int pfIdx, bool doPf) {
    float4v x[4];
#pragma unroll
    for (int mt = 0; mt < 4; ++mt)
#pragma unroll
      for (int e = 0; e < 4; ++e) x[mt][e] = __expf(buf[slot][mt][e]);
    if (doPf) PF(slot, pfIdx);
    CORE(x);
  };

  // prologue: fill ring with steps 0..3
#pragma unroll
  for (int k = 0; k < 4; ++k) PF(k, k);

  for (int idx = 0; idx < WARM; idx += 4) {  // steps 0..47
#pragma unroll
    for (int k = 0; k < 4; ++k) STEP(k, idx + k + 4, true);
  }

  // main-region start: capture scale / exact chunk-0 init
  sS = __log2f(q0cur) + (float)(6 + esum - 116 * nsteps);
  if (c == 0) {  // divergent, but no cross-lane ops inside
    float aref = startT[0] + emB[0];
    gamma = aref * LOG2E;
    sS = 0.f;
    esum = 0;
    nsteps = 0;
    q0cur = 0.015625f;
#pragma unroll
    for (int e = 0; e < 8; ++e) {
      int t0i = 16 * (e >> 2) + 4 * g + (e & 3);
      B0[e] = (__fp16)(__expf(startT[t0i] + emB[t0i] - aref) * 0.015625f);
      B1[e] = (__fp16)(__expf(startT[t0i + 32] + emB[t0i + 32] - aref) *
                       0.015625f);
    }
  }

  for (int idx = WARM; idx < NSTEP - 4; idx += 4) {  // steps 48..75
#pragma unroll
    for (int k = 0; k < 4; ++k) STEP(k, idx + k + 4, true);  // pf up to 79
  }
  // steps 76..78 (always in range: p <= c*32+30 <= 2046... and 78 -> 2047)
  STEP(0, 0, false);
  STEP(1, 0, false);
  STEP(2, 0, false);
  {  // step 79: OOB for chunk 63 (p=2048) — convergent compute, predicated commit
    half8v oB0 = B0, oB1 = B1;
    float4v o0 = tf0, o1 = tf1, o2 = tf2, o3 = tf3;
    int oes = esum, on = nsteps;
    float oq = q0cur;
    STEP(3, 0, false);
    int p = base + (NSTEP - 1);
    int pc = p > SS - 1 ? SS - 1 : p;
    bool act = (p >= 1) && (p <= SS - 1) && (mask[rowb + pc] != 0);
    if (!act) {
      B0 = oB0; B1 = oB1; esum = oes; nsteps = on; q0cur = oq;
      tf0 = o0; tf1 = o1; tf2 = o2; tf3 = o3;
    }
  }

  // chunk contribution: V_c = ln2 * (eS - sS)
  float eS = __log2f(q0cur) + (float)(6 + esum - 116 * nsteps) + gamma;
  float contrib = LN2 * (eS - sS);

  // final logsumexp (only c==KC-1 streams use it; computed convergently)
  {
    float q0l = __log2f(q0cur);
    float4v ar0, ar1, ar2, ar3;
    float mx = -1e30f;
#pragma unroll
    for (int r = 0; r < 4; ++r) {
      ar0[r] = LN2 * (__log2f(tf0[r]) - q0l) + endT[4 * g + r];
      ar1[r] = LN2 * (__log2f(tf1[r]) - q0l) + endT[16 + 4 * g + r];
      ar2[r] = LN2 * (__log2f(tf2[r]) - q0l) + endT[32 + 4 * g + r];
      ar3[r] = LN2 * (__log2f(tf3[r]) - q0l) + endT[48 + 4 * g + r];
      mx = fmaxf(mx, fmaxf(fmaxf(ar0[r], ar1[r]), fmaxf(ar2[r], ar3[r])));
    }
    mx = fmaxf(mx, __shfl_xor(mx, 16, 64));
    mx = fmaxf(mx, __shfl_xor(mx, 32, 64));
    float ex = 0.f;
#pragma unroll
    for (int r = 0; r < 4; ++r)
      ex += __expf(ar0[r] - mx) + __expf(ar1[r] - mx) + __expf(ar2[r] - mx) +
            __expf(ar3[r] - mx);
    ex += __shfl_xor(ex, 16, 64);
    ex += __shfl_xor(ex, 32, 64);
    if (c == KC - 1) contrib += mx + __logf(ex);
  }

  // one atomic per wave: sum contribs of the 16 streams (g==0 lanes only)
  float val = (g == 0) ? contrib : 0.f;
#pragma unroll
  for (int o = 32; o > 0; o >>= 1) val += __shfl_xor(val, o, 64);
  if (lane == 0)
    atomicAdd(acc + (size_t)(blockIdx.x & slotmask) * SLOT_STRIDE,
              val * (1.0f / BB));
}

__global__ __launch_bounds__(64) void reduce_kernel(const float* __restrict__ ws,
                                                    float* __restrict__ out) {
  float v = ws[(size_t)threadIdx.x * SLOT_STRIDE] +
            ws[(size_t)(threadIdx.x + 64) * SLOT_STRIDE];
#pragma unroll
  for (int o = 32; o > 0; o >>= 1) v += __shfl_xor(v, o, 64);
  if (threadIdx.x == 0) *out = v;
}

extern "C" void kernel_launch(void* const* d_in, const int* in_sizes, int n_in,
                              void* d_out, int out_size, void* d_ws, size_t ws_size,
                              hipStream_t stream) {
  const float* em = (const float*)d_in[0];
  const float* startT = (const float*)d_in[1];
  const float* endT = (const float*)d_in[2];
  const float* trans = (const float*)d_in[3];
  const int* tags = (const int*)d_in[4];
  const int* mask = (const int*)d_in[5];
  float* out = (float*)d_out;

  const size_t need = (size_t)NSLOT * SLOT_STRIDE * sizeof(float);
  if (d_ws && ws_size >= need) {
    (void)hipMemsetAsync(d_ws, 0, need, stream);
    crf_kernel<<<DEN_WAVES + BB, 64, 0, stream>>>(em, startT, endT, trans, tags,
                                                  mask, (float*)d_ws, NSLOT - 1);
    reduce_kernel<<<1, 64, 0, stream>>>((const float*)d_ws, out);
  } else {  // tiny-workspace fallback: single accumulator
    (void)hipMemsetAsync(out, 0, sizeof(float), stream);
    crf_kernel<<<DEN_WAVES + BB, 64, 0, stream>>>(em, startT, endT, trans, tags,
                                                  mask, out, 0);
  }
}